// Round 1
// baseline (9289.462 us; speedup 1.0000x reference)
//
#include <hip/hip_runtime.h>
#include <hip/hip_bf16.h>

#define HID 4096
#define NEMBD 64
#define NBATCH 32
#define NTIME 64
#define NVOCAB 256
#define G4 16384

typedef __attribute__((ext_vector_type(4))) float f32x4;
typedef __attribute__((ext_vector_type(8))) short s16x8;

__device__ __forceinline__ unsigned short f2bf(float f) {
  union { float f; unsigned u; } v; v.f = f;
  unsigned u = v.u + 0x7FFFu + ((v.u >> 16) & 1u);
  return (unsigned short)(u >> 16);
}

// A-fragment packed offset for a [32 rows][4096 k] bf16 matrix, chunked by 32k:
// chunk*1024 + tile512*(row>=16) + lane*8 + elem, lane = (row&15) | (((k>>3)&3)<<4)
__device__ __forceinline__ int apoff(int b, int j) {
  return ((j >> 5) << 10) | ((b >> 4) << 9) |
         (((b & 15) | (((j >> 3) & 3) << 4)) << 3) | (j & 7);
}

// ---------------- column-wise weight-norm scale: g[j] / sqrt(max(sum w^2, 1e-12)) ----
__global__ void colscale_k(const float* __restrict__ w, const float* __restrict__ g,
                           float* __restrict__ scale, int K, int N) {
  int j = blockIdx.x * 256 + threadIdx.x;
  if (j >= N) return;
  float s = 0.f;
  for (int k = 0; k < K; ++k) { float v = w[(size_t)k * N + j]; s += v * v; }
  s = fmaxf(s, 1e-12f);
  scale[j] = g ? (g[j] / sqrtf(s)) : (1.f / sqrtf(s));
}

// ---------------- pack fp32 [K][N] column-slice into bf16 B-fragment order -----------
// block bid: colbase = (bid&3)*Cw + (bid>>S)*16 ; kbase = (bid&3)*Kw ; nch chunks of 32k
__global__ void pack_k(const float* __restrict__ src, const float* __restrict__ scale,
                       unsigned short* __restrict__ dst, int N, int Cw, int S, int Kw,
                       int nch) {
  int bid = blockIdx.x;
  int colbase = (bid & 3) * Cw + (bid >> S) * 16;
  int kbase = (bid & 3) * Kw;
  size_t dstbase = (size_t)bid * nch * 512;
  __shared__ unsigned short tile[512];
  int tid = threadIdx.x;
  int col16 = tid & 15, kk = tid >> 4;  // kk in 0..15
  float sc = scale ? scale[colbase + col16] : 1.f;
  for (int c = 0; c < nch; ++c) {
    for (int h = 0; h < 2; ++h) {
      int kk2 = kk + h * 16;  // 0..31 within chunk
      int k = kbase + c * 32 + kk2;
      float v = src[(size_t)k * N + colbase + col16] * sc;
      int l = col16 | (((kk2 >> 3) & 3) << 4);
      tile[l * 8 + (kk2 & 7)] = f2bf(v);
    }
    __syncthreads();
    if (tid < 64)
      ((s16x8*)(dst + dstbase + (size_t)c * 512))[tid] = ((s16x8*)tile)[tid];
    __syncthreads();
  }
}

// ---------------- embed X and pack x_t [32][64] into A-fragment order per t ----------
__global__ void xepack_k(const int* __restrict__ X, const float* __restrict__ embd,
                         unsigned short* __restrict__ xe) {
  int t = blockIdx.x;
  int tid = threadIdx.x;
  int l = tid & 63, tile = (tid >> 6) & 1, c2 = tid >> 7;
  int b = tile * 16 + (l & 15);
  int row = X[b * NTIME + t];
  int k0 = 32 * c2 + 8 * (l >> 4);
  size_t off = (size_t)t * 2048 + c2 * 1024 + tile * 512 + l * 8;
  for (int j = 0; j < 8; ++j) xe[off + j] = f2bf(embd[row * NEMBD + k0 + j]);
}

// ---------------- init states + barrier ---------------------------------------------
__global__ void init_k(const float* __restrict__ S, float* __restrict__ cst,
                       float* __restrict__ hst, unsigned short* __restrict__ hpk,
                       unsigned int* __restrict__ bar) {
  int e = blockIdx.x * 256 + threadIdx.x;
  if (e < NBATCH * HID) {
    float c = S[e], h = S[NBATCH * HID + e];
    cst[e] = c; hst[e] = h;
    int b = e >> 12, j = e & 4095;
    hpk[apoff(b, j)] = f2bf(h);
  }
  if (blockIdx.x == 0 && threadIdx.x < 2) bar[threadIdx.x] = 0u;
}

// ---------------- grid barrier (sense via generation counter) ------------------------
__device__ __forceinline__ void gridbar(unsigned int* bar) {
  __syncthreads();
  if (threadIdx.x == 0) {
    __threadfence();
    unsigned g = __hip_atomic_load(&bar[1], __ATOMIC_ACQUIRE, __HIP_MEMORY_SCOPE_AGENT);
    unsigned a = __hip_atomic_fetch_add(&bar[0], 1u, __ATOMIC_ACQ_REL, __HIP_MEMORY_SCOPE_AGENT);
    if (a == 255u) {
      __hip_atomic_store(&bar[0], 0u, __ATOMIC_RELAXED, __HIP_MEMORY_SCOPE_AGENT);
      __hip_atomic_store(&bar[1], g + 1u, __ATOMIC_RELEASE, __HIP_MEMORY_SCOPE_AGENT);
    } else {
      while (__hip_atomic_load(&bar[1], __ATOMIC_ACQUIRE, __HIP_MEMORY_SCOPE_AGENT) == g)
        __builtin_amdgcn_s_sleep(2);
    }
  }
  __syncthreads();
}

#define MFMA(a, b, c) __builtin_amdgcn_mfma_f32_16x16x32_bf16(a, b, c, 0, 0, 0)

// ---------------- persistent recurrence: 64 steps, 2 grid barriers per step ----------
__global__ __launch_bounds__(256, 1)
void rec_k(const unsigned short* __restrict__ whp, const unsigned short* __restrict__ wmhp,
           const unsigned short* __restrict__ wxp, const unsigned short* __restrict__ wmxp,
           const unsigned short* __restrict__ xe, const float* __restrict__ bias,
           const float* __restrict__ Mm, unsigned short* __restrict__ mpk,
           unsigned short* __restrict__ hpk, float* __restrict__ cst,
           float* __restrict__ hst, unsigned short* __restrict__ hflat,
           float* __restrict__ out, unsigned int* __restrict__ bar) {
  const int g = blockIdx.x;
  const int tid = threadIdx.x;
  const int w = tid >> 6, l = tid & 63;
  const int lo = l & 15, hi = l >> 4;

  __shared__ float zt[4][32][16];
  __shared__ float hmp[4][32][16];
  __shared__ float xmS[32][16];

  const s16x8* wmh_w = (const s16x8*)(wmhp + (size_t)(g * 4 + w) * 32 * 512);
  const s16x8* wh_w  = (const s16x8*)(whp  + (size_t)(g * 4 + w) * 128 * 512);
  const s16x8* wx_w  = (const s16x8*)(wxp  + (size_t)(g * 4 + w) * 2 * 512);
  const s16x8* wmx_g = (const s16x8*)(wmxp + (size_t)g * 2 * 512);
  const float bv = bias[w * 4096 + g * 16 + lo];

  for (int t = 0; t < NTIME; ++t) {
    // ---- phase 1: hm = h @ wmhn (K split over waves), m = xm * hm ----
    f32x4 a0 = {0.f, 0.f, 0.f, 0.f}, a1 = {0.f, 0.f, 0.f, 0.f};
    {
      const s16x8* hp = (const s16x8*)hpk;
#pragma unroll 4
      for (int c = 0; c < 32; ++c) {
        s16x8 bf = wmh_w[c * 64 + l];
        s16x8 af0 = hp[(w * 32 + c) * 128 + l];
        s16x8 af1 = hp[(w * 32 + c) * 128 + 64 + l];
        a0 = MFMA(af0, bf, a0);
        a1 = MFMA(af1, bf, a1);
      }
    }
#pragma unroll
    for (int r = 0; r < 4; ++r) {
      hmp[w][4 * hi + r][lo] = a0[r];
      hmp[w][16 + 4 * hi + r][lo] = a1[r];
    }
    if (w == 0) {  // xm = x_t @ wmxn (K=64)
      f32x4 x0 = {0.f, 0.f, 0.f, 0.f}, x1 = {0.f, 0.f, 0.f, 0.f};
      const s16x8* xep = (const s16x8*)(xe + (size_t)t * 2048);
#pragma unroll
      for (int c2 = 0; c2 < 2; ++c2) {
        s16x8 bf = wmx_g[c2 * 64 + l];
        x0 = MFMA(xep[c2 * 128 + l], bf, x0);
        x1 = MFMA(xep[c2 * 128 + 64 + l], bf, x1);
      }
#pragma unroll
      for (int r = 0; r < 4; ++r) {
        xmS[4 * hi + r][lo] = x0[r];
        xmS[16 + 4 * hi + r][lo] = x1[r];
      }
    }
    __syncthreads();
    for (int e = tid; e < 512; e += 256) {
      int b = e >> 4, col = e & 15;
      float hm = hmp[0][b][col] + hmp[1][b][col] + hmp[2][b][col] + hmp[3][b][col];
      mpk[apoff(b, g * 16 + col)] = f2bf(xmS[b][col] * hm);
    }
    gridbar(bar);

    // ---- phase 2: z = x@wxn + m@whn + b ; gates ; state update ----
    f32x4 z0 = {0.f, 0.f, 0.f, 0.f}, z1 = {0.f, 0.f, 0.f, 0.f};
    {
      const s16x8* mp = (const s16x8*)mpk;
#pragma unroll 4
      for (int c = 0; c < 128; ++c) {
        s16x8 bf = wh_w[c * 64 + l];
        s16x8 af0 = mp[c * 128 + l];
        s16x8 af1 = mp[c * 128 + 64 + l];
        z0 = MFMA(af0, bf, z0);
        z1 = MFMA(af1, bf, z1);
      }
      const s16x8* xep = (const s16x8*)(xe + (size_t)t * 2048);
#pragma unroll
      for (int c2 = 0; c2 < 2; ++c2) {
        s16x8 bf = wx_w[c2 * 64 + l];
        z0 = MFMA(xep[c2 * 128 + l], bf, z0);
        z1 = MFMA(xep[c2 * 128 + 64 + l], bf, z1);
      }
    }
#pragma unroll
    for (int r = 0; r < 4; ++r) {
      zt[w][4 * hi + r][lo] = z0[r] + bv;
      zt[w][16 + 4 * hi + r][lo] = z1[r] + bv;
    }
    __syncthreads();
    for (int e = tid; e < 512; e += 256) {
      int b = e >> 4, col = e & 15;
      int j = g * 16 + col;
      float iv = zt[0][b][col], fv = zt[1][b][col], ov = zt[2][b][col], uv = zt[3][b][col];
      iv = 1.f / (1.f + __expf(-iv));
      fv = 1.f / (1.f + __expf(-fv));
      ov = 1.f / (1.f + __expf(-ov));
      uv = tanhf(uv);
      size_t sj = (size_t)b * HID + j;
      float cp = cst[sj], hp = hst[sj];
      float ct = fv * cp + iv * uv;
      float ht = ov * tanhf(ct);
      float mt = Mm[b * NTIME + t];
      float cn = ct * mt + cp * (1.f - mt);
      float hn = ht * mt + hp * (1.f - mt);
      cst[sj] = cn; hst[sj] = hn;
      out[((size_t)t * NBATCH + b) * HID + j] = cn;                       // cells
      hflat[((size_t)b * NTIME + t) * HID + j] = f2bf(hn);
      hpk[apoff(b, j)] = f2bf(hn);
      if (t == NTIME - 1) {
        out[(size_t)NTIME * NBATCH * HID + sj] = cn;                      // states[0]
        out[(size_t)NTIME * NBATCH * HID + NBATCH * HID + sj] = hn;       // states[1]
      }
    }
    gridbar(bar);
  }
}

// ---------------- logits = hflat @ w_out + b_out  ([2048,4096]x[4096,256]) -----------
__global__ __launch_bounds__(256)
void logits_k(const unsigned short* __restrict__ hflat,
              const unsigned short* __restrict__ woutp,
              const float* __restrict__ bout, float* __restrict__ out) {
  int r0 = blockIdx.x * 16;
  int tid = threadIdx.x, w = tid >> 6, l = tid & 63;
  int lo = l & 15, hi = l >> 4;
  f32x4 acc[4] = {{0.f,0.f,0.f,0.f},{0.f,0.f,0.f,0.f},{0.f,0.f,0.f,0.f},{0.f,0.f,0.f,0.f}};
  const unsigned short* arow = hflat + (size_t)(r0 + lo) * HID;
  const s16x8* wp = (const s16x8*)woutp;
#pragma unroll 2
  for (int c = 0; c < 128; ++c) {
    s16x8 af = *(const s16x8*)(arow + c * 32 + 8 * hi);
#pragma unroll
    for (int q = 0; q < 4; ++q) {
      int nt = w * 4 + q;
      acc[q] = MFMA(af, wp[(nt * 128 + c) * 64 + l], acc[q]);
    }
  }
#pragma unroll
  for (int q = 0; q < 4; ++q) {
    int nt = w * 4 + q;
    int col = nt * 16 + lo;
    float bo = bout[col];
#pragma unroll
    for (int r = 0; r < 4; ++r)
      out[(size_t)(r0 + 4 * hi + r) * NVOCAB + col] = acc[q][r] + bo;
  }
}

extern "C" void kernel_launch(void* const* d_in, const int* in_sizes, int n_in,
                              void* d_out, int out_size, void* d_ws, size_t ws_size,
                              hipStream_t stream) {
  const int*   X    = (const int*)d_in[0];
  const float* Mm   = (const float*)d_in[1];
  const float* S    = (const float*)d_in[2];
  const float* embd = (const float*)d_in[3];
  const float* wx   = (const float*)d_in[4];
  const float* wh   = (const float*)d_in[5];
  const float* wmx  = (const float*)d_in[6];
  const float* wmh  = (const float*)d_in[7];
  const float* b    = (const float*)d_in[8];
  const float* gx   = (const float*)d_in[9];
  const float* gh   = (const float*)d_in[10];
  const float* gmx  = (const float*)d_in[11];
  const float* gmh  = (const float*)d_in[12];
  const float* wout = (const float*)d_in[13];
  const float* bout = (const float*)d_in[14];
  float* out = (float*)d_out;
  char* ws = (char*)d_ws;

  size_t cur = 0;
  auto alloc = [&](size_t bytes) { size_t o = cur; cur += (bytes + 255) & ~size_t(255); return o; };
  unsigned short* WHP   = (unsigned short*)(ws + alloc((size_t)1024 * 128 * 512 * 2)); // 128MB
  unsigned short* WMHP  = (unsigned short*)(ws + alloc((size_t)1024 * 32 * 512 * 2));  // 32MB
  unsigned short* WXP   = (unsigned short*)(ws + alloc((size_t)1024 * 2 * 512 * 2));   // 2MB
  unsigned short* WMXP  = (unsigned short*)(ws + alloc((size_t)256 * 2 * 512 * 2));    // 0.5MB
  unsigned short* WOUTP = (unsigned short*)(ws + alloc((size_t)16 * 128 * 512 * 2));   // 2MB
  unsigned short* XE    = (unsigned short*)(ws + alloc((size_t)64 * 2048 * 2));        // 256KB
  unsigned short* MPK   = (unsigned short*)(ws + alloc((size_t)32 * 4096 * 2));        // 256KB
  unsigned short* HPK   = (unsigned short*)(ws + alloc((size_t)32 * 4096 * 2));        // 256KB
  float* CST            = (float*)(ws + alloc((size_t)32 * 4096 * 4));
  float* HST            = (float*)(ws + alloc((size_t)32 * 4096 * 4));
  unsigned short* HFLAT = (unsigned short*)(ws + alloc((size_t)2048 * 4096 * 2));      // 16MB
  float* SX             = (float*)(ws + alloc(16384 * 4));
  float* SH             = (float*)(ws + alloc(16384 * 4));
  float* SMX            = (float*)(ws + alloc(4096 * 4));
  float* SMH            = (float*)(ws + alloc(4096 * 4));
  unsigned int* BAR     = (unsigned int*)(ws + alloc(256));
  (void)ws_size; (void)in_sizes; (void)n_in; (void)out_size;

  // weight-norm scales
  colscale_k<<<64, 256, 0, stream>>>(wx, gx, SX, 64, G4);
  colscale_k<<<64, 256, 0, stream>>>(wh, gh, SH, HID, G4);
  colscale_k<<<16, 256, 0, stream>>>(wmx, gmx, SMX, 64, HID);
  colscale_k<<<16, 256, 0, stream>>>(wmh, gmh, SMH, HID, HID);

  // pack weights into bf16 fragment order
  pack_k<<<1024, 256, 0, stream>>>(wh,  SH,  WHP,  G4,  4096, 2, 0,    128);
  pack_k<<<1024, 256, 0, stream>>>(wmh, SMH, WMHP, HID, 0,    2, 1024, 32);
  pack_k<<<1024, 256, 0, stream>>>(wx,  SX,  WXP,  G4,  4096, 2, 0,    2);
  pack_k<<<256,  256, 0, stream>>>(wmx, SMX, WMXP, HID, 0,    0, 0,    2);
  pack_k<<<16,   256, 0, stream>>>(wout, nullptr, WOUTP, NVOCAB, 0, 0, 0, 128);

  xepack_k<<<64, 256, 0, stream>>>(X, embd, XE);
  init_k<<<512, 256, 0, stream>>>(S, CST, HST, HPK, BAR);

  rec_k<<<256, 256, 0, stream>>>(WHP, WMHP, WXP, WMXP, XE, b, Mm, MPK, HPK, CST, HST,
                                 HFLAT, out, BAR);

  logits_k<<<128, 256, 0, stream>>>(HFLAT, WOUTP, bout,
                                    out + (size_t)NTIME * NBATCH * HID + 2 * NBATCH * HID);
}

// Round 2
// 6177.699 us; speedup vs baseline: 1.5037x; 1.5037x over previous
//
#include <hip/hip_runtime.h>
#include <hip/hip_bf16.h>

#define HID 4096
#define NEMBD 64
#define NBATCH 32
#define NTIME 64
#define NVOCAB 256
#define G4 16384

typedef __attribute__((ext_vector_type(4))) float f32x4;
typedef __attribute__((ext_vector_type(8))) short s16x8;

__device__ __forceinline__ unsigned short f2bf(float f) {
  union { float f; unsigned u; } v; v.f = f;
  unsigned u = v.u + 0x7FFFu + ((v.u >> 16) & 1u);
  return (unsigned short)(u >> 16);
}

// A-fragment packed offset for a [32 rows][4096 k] bf16 matrix, chunked by 32k:
// chunk*1024 + tile512*(row>=16) + lane*8 + elem, lane = (row&15) | (((k>>3)&3)<<4)
__device__ __forceinline__ int apoff(int b, int j) {
  return ((j >> 5) << 10) | ((b >> 4) << 9) |
         (((b & 15) | (((j >> 3) & 3) << 4)) << 3) | (j & 7);
}

// ---------------- stage 1: partial column sums of squares (deterministic K-split) ----
// grid (N/64, KS); block 256 = 64 cols x 4 kgroups; ss[ky][j] = sum over k-slice
__global__ void colsum_k(const float* __restrict__ w, float* __restrict__ ss,
                         int K, int N, int KS) {
  int col = threadIdx.x & 63, kg = threadIdx.x >> 6;
  int j = blockIdx.x * 64 + col;
  int kper = K / KS;
  int k0 = blockIdx.y * kper;
  float s = 0.f;
#pragma unroll 4
  for (int k = k0 + kg; k < k0 + kper; k += 4) {
    float v = w[(size_t)k * N + j];
    s += v * v;
  }
  __shared__ float red[4][64];
  red[kg][col] = s;
  __syncthreads();
  if (threadIdx.x < 64)
    ss[(size_t)blockIdx.y * N + j] = red[0][col] + red[1][col] + red[2][col] + red[3][col];
}

// ---------------- pack fp32 [K][N] column-slice into bf16 B-fragment order -----------
// block bid: colbase=(bid&3)*Cw+(bid>>S)*16; kbase=(bid&3)*Kw; nch chunks of 32k,
// chunk range split over gridDim.y. Scale finalized from partial sums ss (KS slices).
__global__ void pack_k(const float* __restrict__ src, const float* __restrict__ ss,
                       const float* __restrict__ g, unsigned short* __restrict__ dst,
                       int N, int Cw, int S, int Kw, int nch, int KS) {
  int bid = blockIdx.x;
  int colbase = (bid & 3) * Cw + (bid >> S) * 16;
  int kbase = (bid & 3) * Kw;
  int cper = nch / gridDim.y;
  int c0 = blockIdx.y * cper;
  size_t dstbase = (size_t)bid * nch * 512 + (size_t)c0 * 512;
  __shared__ unsigned short tile[512];
  int tid = threadIdx.x;
  int col16 = tid & 15, kk = tid >> 4;  // kk in 0..15
  float sc = 1.f;
  if (ss) {
    float t = 0.f;
    for (int q = 0; q < KS; ++q) t += ss[(size_t)q * N + colbase + col16];
    sc = g[colbase + col16] / sqrtf(fmaxf(t, 1e-12f));
  }
  for (int c = c0; c < c0 + cper; ++c) {
    for (int h = 0; h < 2; ++h) {
      int kk2 = kk + h * 16;  // 0..31 within chunk
      int k = kbase + c * 32 + kk2;
      float v = src[(size_t)k * N + colbase + col16] * sc;
      int l = col16 | (((kk2 >> 3) & 3) << 4);
      tile[l * 8 + (kk2 & 7)] = f2bf(v);
    }
    __syncthreads();
    if (tid < 64)
      ((s16x8*)(dst + dstbase + (size_t)(c - c0) * 512))[tid] = ((s16x8*)tile)[tid];
    __syncthreads();
  }
}

// ---------------- embed X and pack x_t [32][64] into A-fragment order per t ----------
__global__ void xepack_k(const int* __restrict__ X, const float* __restrict__ embd,
                         unsigned short* __restrict__ xe) {
  int t = blockIdx.x;
  int tid = threadIdx.x;
  int l = tid & 63, tile = (tid >> 6) & 1, c2 = tid >> 7;
  int b = tile * 16 + (l & 15);
  int row = X[b * NTIME + t];
  int k0 = 32 * c2 + 8 * (l >> 4);
  size_t off = (size_t)t * 2048 + c2 * 1024 + tile * 512 + l * 8;
  for (int j = 0; j < 8; ++j) xe[off + j] = f2bf(embd[row * NEMBD + k0 + j]);
}

// ---------------- init states + barrier ---------------------------------------------
__global__ void init_k(const float* __restrict__ S, float* __restrict__ cst,
                       float* __restrict__ hst, unsigned short* __restrict__ hpk,
                       unsigned int* __restrict__ bar) {
  int e = blockIdx.x * 256 + threadIdx.x;
  if (e < NBATCH * HID) {
    float c = S[e], h = S[NBATCH * HID + e];
    cst[e] = c; hst[e] = h;
    int b = e >> 12, j = e & 4095;
    hpk[apoff(b, j)] = f2bf(h);
  }
  if (blockIdx.x == 0 && threadIdx.x < 2) bar[threadIdx.x] = 0u;
}

// ---------------- grid barrier (sense via generation counter) ------------------------
__device__ __forceinline__ void gridbar(unsigned int* bar) {
  __syncthreads();
  if (threadIdx.x == 0) {
    __threadfence();
    unsigned g = __hip_atomic_load(&bar[1], __ATOMIC_ACQUIRE, __HIP_MEMORY_SCOPE_AGENT);
    unsigned a = __hip_atomic_fetch_add(&bar[0], 1u, __ATOMIC_ACQ_REL, __HIP_MEMORY_SCOPE_AGENT);
    if (a == 255u) {
      __hip_atomic_store(&bar[0], 0u, __ATOMIC_RELAXED, __HIP_MEMORY_SCOPE_AGENT);
      __hip_atomic_store(&bar[1], g + 1u, __ATOMIC_RELEASE, __HIP_MEMORY_SCOPE_AGENT);
    } else {
      while (__hip_atomic_load(&bar[1], __ATOMIC_ACQUIRE, __HIP_MEMORY_SCOPE_AGENT) == g)
        __builtin_amdgcn_s_sleep(2);
    }
  }
  __syncthreads();
}

#define MFMA(a, b, c) __builtin_amdgcn_mfma_f32_16x16x32_bf16(a, b, c, 0, 0, 0)

// ---------------- persistent recurrence: 64 steps, 2 grid barriers per step ----------
// 256 blocks x 1024 threads (16 waves). Phase 1: hm = h@wmhn, K split 16 ways, weights
// register-resident. Phase 2: z = x@wxn + m@whn, wave w: gate=w&3, K-quarter ks=w>>2.
__global__ __launch_bounds__(1024, 4)
void rec_k(const unsigned short* __restrict__ whp, const unsigned short* __restrict__ wmhp,
           const unsigned short* __restrict__ wxp, const unsigned short* __restrict__ wmxp,
           const unsigned short* __restrict__ xe, const float* __restrict__ bias,
           const float* __restrict__ Mm, unsigned short* __restrict__ mpk,
           unsigned short* __restrict__ hpk, float* __restrict__ cst,
           float* __restrict__ hst, unsigned short* __restrict__ hflat,
           float* __restrict__ out, unsigned int* __restrict__ bar) {
  const int g = blockIdx.x;
  const int tid = threadIdx.x;
  const int w = tid >> 6, l = tid & 63;
  const int lo = l & 15, hi = l >> 4;
  const int gate = w & 3, ks = w >> 2;

  __shared__ float part[16][32][16];
  __shared__ float xmS[32][16];

  const s16x8* wmh_g = (const s16x8*)(wmhp + (size_t)g * 128 * 512);
  const s16x8* wh_w  = (const s16x8*)(whp  + (size_t)(g * 4 + gate) * 128 * 512);
  const s16x8* wx_w  = (const s16x8*)(wxp  + (size_t)(g * 4 + gate) * 2 * 512);
  const s16x8* wmx_g = (const s16x8*)(wmxp + (size_t)g * 2 * 512);

  // phase-1 weights: register-resident for the whole kernel (8 x 16B/lane)
  s16x8 wmhr[8];
#pragma unroll
  for (int q = 0; q < 8; ++q) wmhr[q] = wmh_g[(w * 8 + q) * 64 + l];

  // epilogue constants (threads 0..511: eb = batch, ecol = col-in-tile)
  const int eb = tid >> 4, ecol = tid & 15;
  const int ej = g * 16 + ecol;
  float bI = 0.f, bF = 0.f, bO = 0.f, bU = 0.f;
  if (tid < 512) {
    bI = bias[ej]; bF = bias[4096 + ej]; bO = bias[8192 + ej]; bU = bias[12288 + ej];
  }

  for (int t = 0; t < NTIME; ++t) {
    // A: prefetch first 8 phase-2 weight chunks (independent of the barrier)
    s16x8 pre[8];
#pragma unroll
    for (int q = 0; q < 8; ++q) pre[q] = wh_w[(ks * 32 + q) * 64 + l];

    // B: phase 1 — hm partials on resident weights (A-operand from L2-hot hpk)
    f32x4 a0 = {0.f, 0.f, 0.f, 0.f}, a1 = {0.f, 0.f, 0.f, 0.f};
    {
      const s16x8* hp = (const s16x8*)hpk;
#pragma unroll
      for (int q = 0; q < 8; ++q) {
        int cc = w * 8 + q;
        a0 = MFMA(hp[cc * 128 + l], wmhr[q], a0);
        a1 = MFMA(hp[cc * 128 + 64 + l], wmhr[q], a1);
      }
    }
#pragma unroll
    for (int r = 0; r < 4; ++r) {
      part[w][4 * hi + r][lo] = a0[r];
      part[w][16 + 4 * hi + r][lo] = a1[r];
    }
    if (w == 0) {  // xm = x_t @ wmxn (K=64)
      f32x4 x0 = {0.f, 0.f, 0.f, 0.f}, x1 = {0.f, 0.f, 0.f, 0.f};
      const s16x8* xep = (const s16x8*)(xe + (size_t)t * 2048);
#pragma unroll
      for (int c2 = 0; c2 < 2; ++c2) {
        s16x8 bf = wmx_g[c2 * 64 + l];
        x0 = MFMA(xep[c2 * 128 + l], bf, x0);
        x1 = MFMA(xep[c2 * 128 + 64 + l], bf, x1);
      }
#pragma unroll
      for (int r = 0; r < 4; ++r) {
        xmS[4 * hi + r][lo] = x0[r];
        xmS[16 + 4 * hi + r][lo] = x1[r];
      }
    }
    __syncthreads();
    if (tid < 512) {
      float hm = 0.f;
#pragma unroll
      for (int k = 0; k < 16; ++k) hm += part[k][eb][ecol];
      mpk[apoff(eb, ej)] = f2bf(xmS[eb][ecol] * hm);
    }
    gridbar(bar);

    // phase 2: z partials — first 8 chunks from prefetched regs, then stream 24
    f32x4 z0 = {0.f, 0.f, 0.f, 0.f}, z1 = {0.f, 0.f, 0.f, 0.f};
    {
      const s16x8* mp = (const s16x8*)mpk;
#pragma unroll
      for (int q = 0; q < 8; ++q) {
        int cc = ks * 32 + q;
        z0 = MFMA(mp[cc * 128 + l], pre[q], z0);
        z1 = MFMA(mp[cc * 128 + 64 + l], pre[q], z1);
      }
#pragma unroll 4
      for (int q = 8; q < 32; ++q) {
        int cc = ks * 32 + q;
        s16x8 bf = wh_w[cc * 64 + l];
        z0 = MFMA(mp[cc * 128 + l], bf, z0);
        z1 = MFMA(mp[cc * 128 + 64 + l], bf, z1);
      }
      if (ks == 0) {  // x @ wxn contribution (K=64)
        const s16x8* xep = (const s16x8*)(xe + (size_t)t * 2048);
#pragma unroll
        for (int c2 = 0; c2 < 2; ++c2) {
          s16x8 bf = wx_w[c2 * 64 + l];
          z0 = MFMA(xep[c2 * 128 + l], bf, z0);
          z1 = MFMA(xep[c2 * 128 + 64 + l], bf, z1);
        }
      }
    }
#pragma unroll
    for (int r = 0; r < 4; ++r) {
      part[w][4 * hi + r][lo] = z0[r];
      part[w][16 + 4 * hi + r][lo] = z1[r];
    }
    __syncthreads();
    if (tid < 512) {
      float iv = part[0][eb][ecol] + part[4][eb][ecol] + part[8][eb][ecol] + part[12][eb][ecol] + bI;
      float fv = part[1][eb][ecol] + part[5][eb][ecol] + part[9][eb][ecol] + part[13][eb][ecol] + bF;
      float ov = part[2][eb][ecol] + part[6][eb][ecol] + part[10][eb][ecol] + part[14][eb][ecol] + bO;
      float uv = part[3][eb][ecol] + part[7][eb][ecol] + part[11][eb][ecol] + part[15][eb][ecol] + bU;
      iv = 1.f / (1.f + __expf(-iv));
      fv = 1.f / (1.f + __expf(-fv));
      ov = 1.f / (1.f + __expf(-ov));
      uv = tanhf(uv);
      size_t sj = (size_t)eb * HID + ej;
      float cp = cst[sj], hpv = hst[sj];
      float ct = fv * cp + iv * uv;
      float ht = ov * tanhf(ct);
      float mt = Mm[eb * NTIME + t];
      float cn = ct * mt + cp * (1.f - mt);
      float hn = ht * mt + hpv * (1.f - mt);
      cst[sj] = cn; hst[sj] = hn;
      out[((size_t)t * NBATCH + eb) * HID + ej] = cn;                      // cells
      hflat[((size_t)eb * NTIME + t) * HID + ej] = f2bf(hn);
      hpk[apoff(eb, ej)] = f2bf(hn);
      if (t == NTIME - 1) {
        out[(size_t)NTIME * NBATCH * HID + sj] = cn;                       // states[0]
        out[(size_t)NTIME * NBATCH * HID + NBATCH * HID + sj] = hn;        // states[1]
      }
    }
    gridbar(bar);
  }
}

// ---------------- logits = hflat @ w_out + b_out  ([2048,4096]x[4096,256]) -----------
__global__ __launch_bounds__(256)
void logits_k(const unsigned short* __restrict__ hflat,
              const unsigned short* __restrict__ woutp,
              const float* __restrict__ bout, float* __restrict__ out) {
  int r0 = blockIdx.x * 16;
  int tid = threadIdx.x, w = tid >> 6, l = tid & 63;
  int lo = l & 15, hi = l >> 4;
  f32x4 acc[4] = {{0.f,0.f,0.f,0.f},{0.f,0.f,0.f,0.f},{0.f,0.f,0.f,0.f},{0.f,0.f,0.f,0.f}};
  const unsigned short* arow = hflat + (size_t)(r0 + lo) * HID;
  const s16x8* wp = (const s16x8*)woutp;
#pragma unroll 2
  for (int c = 0; c < 128; ++c) {
    s16x8 af = *(const s16x8*)(arow + c * 32 + 8 * hi);
#pragma unroll
    for (int q = 0; q < 4; ++q) {
      int nt = w * 4 + q;
      acc[q] = MFMA(af, wp[(nt * 128 + c) * 64 + l], acc[q]);
    }
  }
#pragma unroll
  for (int q = 0; q < 4; ++q) {
    int nt = w * 4 + q;
    int col = nt * 16 + lo;
    float bo = bout[col];
#pragma unroll
    for (int r = 0; r < 4; ++r)
      out[(size_t)(r0 + 4 * hi + r) * NVOCAB + col] = acc[q][r] + bo;
  }
}

extern "C" void kernel_launch(void* const* d_in, const int* in_sizes, int n_in,
                              void* d_out, int out_size, void* d_ws, size_t ws_size,
                              hipStream_t stream) {
  const int*   X    = (const int*)d_in[0];
  const float* Mm   = (const float*)d_in[1];
  const float* S    = (const float*)d_in[2];
  const float* embd = (const float*)d_in[3];
  const float* wx   = (const float*)d_in[4];
  const float* wh   = (const float*)d_in[5];
  const float* wmx  = (const float*)d_in[6];
  const float* wmh  = (const float*)d_in[7];
  const float* b    = (const float*)d_in[8];
  const float* gx   = (const float*)d_in[9];
  const float* gh   = (const float*)d_in[10];
  const float* gmx  = (const float*)d_in[11];
  const float* gmh  = (const float*)d_in[12];
  const float* wout = (const float*)d_in[13];
  const float* bout = (const float*)d_in[14];
  float* out = (float*)d_out;
  char* ws = (char*)d_ws;

  size_t cur = 0;
  auto alloc = [&](size_t bytes) { size_t o = cur; cur += (bytes + 255) & ~size_t(255); return o; };
  unsigned short* WHP   = (unsigned short*)(ws + alloc((size_t)1024 * 128 * 512 * 2)); // 128MB
  unsigned short* WMHP  = (unsigned short*)(ws + alloc((size_t)1024 * 32 * 512 * 2));  // 32MB
  unsigned short* WXP   = (unsigned short*)(ws + alloc((size_t)1024 * 2 * 512 * 2));   // 2MB
  unsigned short* WMXP  = (unsigned short*)(ws + alloc((size_t)256 * 2 * 512 * 2));    // 0.5MB
  unsigned short* WOUTP = (unsigned short*)(ws + alloc((size_t)16 * 128 * 512 * 2));   // 2MB
  unsigned short* XE    = (unsigned short*)(ws + alloc((size_t)64 * 2048 * 2));        // 256KB
  unsigned short* MPK   = (unsigned short*)(ws + alloc((size_t)32 * 4096 * 2));        // 256KB
  unsigned short* HPK   = (unsigned short*)(ws + alloc((size_t)32 * 4096 * 2));        // 256KB
  float* CST            = (float*)(ws + alloc((size_t)32 * 4096 * 4));
  float* HST            = (float*)(ws + alloc((size_t)32 * 4096 * 4));
  unsigned short* HFLAT = (unsigned short*)(ws + alloc((size_t)2048 * 4096 * 2));      // 16MB
  float* SSH            = (float*)(ws + alloc((size_t)8 * 16384 * 4));
  float* SSMH           = (float*)(ws + alloc((size_t)8 * 4096 * 4));
  float* SSX            = (float*)(ws + alloc((size_t)16384 * 4));
  float* SSMX           = (float*)(ws + alloc((size_t)4096 * 4));
  unsigned int* BAR     = (unsigned int*)(ws + alloc(256));
  (void)ws_size; (void)in_sizes; (void)n_in; (void)out_size;

  // stage-1 column sums of squares (parallel, deterministic)
  colsum_k<<<dim3(256, 8), 256, 0, stream>>>(wh,  SSH,  HID, G4,  8);
  colsum_k<<<dim3(64, 8),  256, 0, stream>>>(wmh, SSMH, HID, HID, 8);
  colsum_k<<<dim3(256, 1), 256, 0, stream>>>(wx,  SSX,  NEMBD, G4,  1);
  colsum_k<<<dim3(64, 1),  256, 0, stream>>>(wmx, SSMX, NEMBD, HID, 1);

  // pack weights into bf16 fragment order (scale finalized in-kernel)
  pack_k<<<dim3(1024, 8), 256, 0, stream>>>(wh,  SSH,  gh,  WHP,  G4,  4096, 2, 0,    128, 8);
  pack_k<<<dim3(1024, 4), 256, 0, stream>>>(wmh, SSMH, gmh, WMHP, HID, 0,    2, 1024, 32,  8);
  pack_k<<<dim3(1024, 1), 256, 0, stream>>>(wx,  SSX,  gx,  WXP,  G4,  4096, 2, 0,    2,   1);
  pack_k<<<dim3(256, 1),  256, 0, stream>>>(wmx, SSMX, gmx, WMXP, HID, 0,    0, 0,    2,   1);
  pack_k<<<dim3(16, 1),   256, 0, stream>>>(wout, nullptr, nullptr, WOUTP, NVOCAB, 0, 0, 0, 128, 0);

  xepack_k<<<64, 256, 0, stream>>>(X, embd, XE);
  init_k<<<512, 256, 0, stream>>>(S, CST, HST, HPK, BAR);

  rec_k<<<256, 1024, 0, stream>>>(WHP, WMHP, WXP, WMXP, XE, b, Mm, MPK, HPK, CST, HST,
                                  HFLAT, out, BAR);

  logits_k<<<128, 256, 0, stream>>>(HFLAT, WOUTP, bout,
                                    out + (size_t)NTIME * NBATCH * HID + 2 * NBATCH * HID);
}